// Round 2
// baseline (14.815 us; speedup 1.0000x reference)
//
#include <hip/hip_runtime.h>

// Hierarchical softmax loss, fully collapsed:
//   out = (1/B) * sum_b sum_{t=0..14} softplus( bit_t ? s_t : -s_t )
// with closed-form gather index (no serial chain):
//   s_t = scores[b, (2^t - 1) + (ci >> (15-t))],  bit_t = (ci >> (14-t)) & 1
// derived from idx_0=2, idx_{t+1} = 2*idx_t - (1 - bit_t), idx_t - 2 above.
//
// Single kernel node + one 4-byte memset node. Cross-block reduction via one
// float atomicAdd per block into d_out[0] (zeroed each call by the memset, so
// graph replays are self-contained).

#define B_ROWS   2048
#define V_COLS   32768
#define CODE_LEN 15

__device__ __forceinline__ float softplus_f(float x) {
    // log(1 + e^x) = max(x,0) + log1p(e^{-|x|})
    return fmaxf(x, 0.0f) + log1pf(expf(-fabsf(x)));
}

__global__ void hsm_fused_kernel(const float* __restrict__ scores,
                                 const int* __restrict__ class_indices,
                                 float* __restrict__ out) {
    const int b = blockIdx.x * blockDim.x + threadIdx.x;  // one thread per row
    const int ci = class_indices[b];
    const float* row = scores + (size_t)b * V_COLS;

    float acc = 0.0f;
#pragma unroll
    for (int t = 0; t < CODE_LEN; ++t) {
        // all 15 gather addresses depend only on ci -> issued in parallel
        const float s = row[((1 << t) - 1) + (ci >> (CODE_LEN - t))];
        const int bit = (ci >> (CODE_LEN - 1 - t)) & 1;
        acc += softplus_f(bit ? s : -s);
    }

    // one wave (64 lanes) per block: down-shuffle reduce
#pragma unroll
    for (int off = 32; off > 0; off >>= 1)
        acc += __shfl_down(acc, off);

    if (threadIdx.x == 0)
        atomicAdd(out, acc * (1.0f / (float)B_ROWS));
}

extern "C" void kernel_launch(void* const* d_in, const int* in_sizes, int n_in,
                              void* d_out, int out_size, void* d_ws, size_t ws_size,
                              hipStream_t stream) {
    const float* scores        = (const float*)d_in[0];
    const int*   class_indices = (const int*)d_in[1];
    float*       out           = (float*)d_out;

    hipMemsetAsync(out, 0, sizeof(float), stream);

    const int threads = 64;                 // one wave per block
    const int blocks  = B_ROWS / threads;   // 32 blocks -> 32 CUs issuing gathers
    hsm_fused_kernel<<<blocks, threads, 0, stream>>>(scores, class_indices, out);
}